// Round 16
// baseline (800.156 us; speedup 1.0000x reference)
//
#include <hip/hip_runtime.h>
#include <hip/hip_bf16.h>
#include <cstdint>
#include <cstddef>

#define NTOK 8192
#define DFEAT 768
#define HW 1024
#define BSZ 8
#define KPSI 512
#define KH 256
#define KF 32
#define KPIX 10
#define NB2 128
#define CANDCAP 128
#define BM2 256
#define BK 64
#define SROWS 2048
#define SJCAP 160

typedef __attribute__((ext_vector_type(8))) short bf16x8_t;
typedef __attribute__((ext_vector_type(4))) float f32x4;

__device__ __forceinline__ bool gt_pair(float va, int ia, float vb, int ib) {
  return (va > vb) || (va == vb && ia < ib);
}
__device__ __forceinline__ bool lt_pair(float va, int ia, float vb, int ib) {
  return (va < vb) || (va == vb && ia < ib);
}

__device__ __forceinline__ void gload_lds16(const void* g, void* l) {
  __builtin_amdgcn_global_load_lds((const __attribute__((address_space(1))) void*)g,
                                   (__attribute__((address_space(3))) void*)l, 16, 0, 0);
}

__device__ __forceinline__ void wave_fence_lds() {
  asm volatile("s_waitcnt lgkmcnt(0)" ::: "memory");
  __builtin_amdgcn_wave_barrier();
}

// ---- normalize + bf16 hi/lo split: Y[row] = [hi(768) | lo(768)] ------------
__global__ __launch_bounds__(256) void ksplit(const float* __restrict__ X,
                                              __hip_bfloat16* __restrict__ Y) {
  int row = blockIdx.x;
  int tid = threadIdx.x;
  const float* x = X + (size_t)row * DFEAT;
  float s = 0.f;
  for (int c = tid; c < DFEAT; c += 256) { float v = x[c]; s += v * v; }
  __shared__ float red[4];
  #pragma unroll
  for (int o = 32; o > 0; o >>= 1) s += __shfl_down(s, o);
  if ((tid & 63) == 0) red[tid >> 6] = s;
  __syncthreads();
  if (tid == 0) red[0] = red[0] + red[1] + red[2] + red[3];
  __syncthreads();
  float nrm = sqrtf(red[0]);
  __hip_bfloat16* y = Y + (size_t)row * (2 * DFEAT);
  for (int c = tid; c < DFEAT; c += 256) {
    float v = x[c] / nrm;
    __hip_bfloat16 hi = __float2bfloat16(v);
    __hip_bfloat16 lo = __float2bfloat16(v - __bfloat162float(hi));
    y[c] = hi;
    y[DFEAT + c] = lo;
  }
}

// ---- pixel features: [cfg][img][pix][8] = r,g,b,dw*x,dw*y,sq,0,0 -----------
__global__ __launch_bounds__(256) void kpixfeat(const float* __restrict__ im,
                                                float* __restrict__ pf) {
  int t = blockIdx.x * 256 + threadIdx.x;
  int img = t >> 10, p = t & 1023;
  float r = (im[((size_t)img * 3 + 0) * HW + p] + 1.0f) * 0.5f;
  float g = (im[((size_t)img * 3 + 1) * HW + p] + 1.0f) * 0.5f;
  float b = (im[((size_t)img * 3 + 2) * HW + p] + 1.0f) * 0.5f;
  float x = (float)(p & 31) * (1.0f / 31.0f);
  float y = (float)(p >> 5) * (1.0f / 31.0f);
  #pragma unroll
  for (int cfg = 0; cfg < 2; cfg++) {
    float dw = cfg ? 0.1f : 2.0f;
    float xx = x * dw, yy = y * dw;
    float sq = r * r + g * g + b * b + xx * xx + yy * yy;
    float* o = pf + (((size_t)cfg * BSZ + img) * HW + p) * 8;
    *(float4*)(o)     = make_float4(r, g, b, xx);
    *(float4*)(o + 4) = make_float4(yy, sq, 0.f, 0.f);
  }
}

// ---- pixel top-10: one wave per (row,cfg), vectorized loads ----------------
__global__ __launch_bounds__(256) void kpixtopk(const float* __restrict__ pf,
                                                unsigned int* __restrict__ bits) {
  int wglobal = blockIdx.x * 4 + (threadIdx.x >> 6);
  int lane = threadIdx.x & 63;
  int cfg = wglobal & 1;
  int gr = wglobal >> 1;
  int img = gr >> 10, i = gr & 1023;
  const float* base = pf + ((size_t)cfg * BSZ + img) * HW * 8;
  float4 fa = *(const float4*)(base + (size_t)i * 8);
  float4 fb = *(const float4*)(base + (size_t)i * 8 + 4);
  float r = fa.x, g = fa.y, b = fa.z, x = fa.w, y = fb.x, sq = fb.y;
  float d[16];
  #pragma unroll
  for (int q = 0; q < 16; q++) {
    int j = q * 64 + lane;
    float4 ja = *(const float4*)(base + (size_t)j * 8);
    float4 jb = *(const float4*)(base + (size_t)j * 8 + 4);
    float dot = r * ja.x + g * ja.y + b * ja.z + x * ja.w + y * jb.x;
    float d2 = fmaxf(sq + jb.y - 2.0f * dot, 0.0f);
    d[q] = (j == i) ? 3.402823e38f : d2;
  }
  for (int k = 0; k < KPIX; k++) {
    float bv = 3.402823e38f; int bj = 1 << 30;
    #pragma unroll
    for (int q = 0; q < 16; q++) {
      int j = q * 64 + lane;
      if (lt_pair(d[q], j, bv, bj)) { bv = d[q]; bj = j; }
    }
    #pragma unroll
    for (int o = 32; o > 0; o >>= 1) {
      float ov = __shfl_down(bv, o); int oj = __shfl_down(bj, o);
      if (lt_pair(ov, oj, bv, bj)) { bv = ov; bj = oj; }
    }
    bj = __shfl(bj, 0);
    if ((bj & 63) == lane) d[bj >> 6] = 3.402823e38f;
    if (lane == 0) {
      atomicOr(&bits[((size_t)img * HW + i) * 32 + (bj >> 5)], 1u << (bj & 31));
      atomicOr(&bits[((size_t)img * HW + bj) * 32 + (i >> 5)], 1u << (i & 31));
    }
  }
}

__global__ __launch_bounds__(256) void kdeg2(const unsigned int* __restrict__ bits,
                                             float* __restrict__ d2n) {
  int i = blockIdx.x * 256 + threadIdx.x;
  int c = 0;
  #pragma unroll
  for (int w = 0; w < 32; w++) c += __popc(bits[(size_t)i * 32 + w]);
  d2n[i] = 1.0f / sqrtf((float)c);
}

// ---- bf16x3 MFMA GEMM, 256x256 tile, 16 waves (4x4), dbuf + counted vmcnt --
// (R11-proven config: BK=64, 128KB LDS, vmcnt(4) depth-2, 0 bank conflicts.)
__global__ __launch_bounds__(1024) void kgemm256(const __hip_bfloat16* __restrict__ X,
                                                 float* __restrict__ C,
                                                 int row0, int nwg) {
  __shared__ __hip_bfloat16 sA[2][BM2 * BK];   // 2 x 32 KB
  __shared__ __hip_bfloat16 sB[2][BM2 * BK];   // 2 x 32 KB
  int cpx = nwg >> 3;
  int flat = blockIdx.x;
  int swz = (flat & 7) * cpx + (flat >> 3);
  int by = swz >> 5, bx = swz & 31;
  int tid = threadIdx.x;
  int wid = tid >> 6, lane = tid & 63;
  int wr = wid >> 2, wc = wid & 3;          // wave tile: 64x64 at (wr*64, wc*64)
  int l15 = lane & 15, l4 = lane >> 4, l7 = lane & 7;
  int srow = tid >> 3, sc = tid & 7;        // staging: 8 threads/row, 128 rows/pass

  f32x4 acc[4][4];
  #pragma unroll
  for (int m = 0; m < 4; m++)
    #pragma unroll
    for (int n = 0; n < 4; n++) acc[m][n] = (f32x4){0.f, 0.f, 0.f, 0.f};

  const size_t arow0 = (size_t)(row0 + by * BM2);
  const size_t brow0 = (size_t)(bx * BM2);

  auto stage = [&](int ks, int buf) {
    int s = ks / 12;
    int k0 = (ks - s * 12) * 64;
    int aoff = (s == 2) ? DFEAT : 0;
    int boff = (s == 1) ? DFEAT : 0;
    #pragma unroll
    for (int i = 0; i < 2; i++) {
      int row = i * 128 + srow;
      int gcol = (sc ^ (row & 7)) * 8;     // inverse-swizzled source (rule #21)
      gload_lds16(X + (arow0 + row) * (2 * DFEAT) + aoff + k0 + gcol,
                  &sA[buf][(size_t)i * 8192 + (tid & ~63) * 8]);
      gload_lds16(X + (brow0 + row) * (2 * DFEAT) + boff + k0 + gcol,
                  &sB[buf][(size_t)i * 8192 + (tid & ~63) * 8]);
    }
  };  // 4 gload_lds per stage

  // depth-2 pipeline: S(ks), S(ks+1) in flight; wait vmcnt(4) => S(ks) landed
  stage(0, 0);
  stage(1, 1);
  for (int ks = 0; ks < 36; ks++) {
    int cur = ks & 1;
    if (ks < 35) { asm volatile("s_waitcnt vmcnt(4)" ::: "memory"); }
    else         { asm volatile("s_waitcnt vmcnt(0)" ::: "memory"); }
    __builtin_amdgcn_sched_barrier(0);
    __builtin_amdgcn_s_barrier();           // all waves: S(ks) landed
    __builtin_amdgcn_sched_barrier(0);
    const char* Ab = (const char*)&sA[cur][0];
    const char* Bb = (const char*)&sB[cur][0];
    #pragma unroll
    for (int kk = 0; kk < 2; kk++) {
      bf16x8_t a[4], b[4];
      int chunk = (l4 + kk * 4) ^ l7;      // swizzled read
      #pragma unroll
      for (int m = 0; m < 4; m++) {
        int rowa = wr * 64 + m * 16 + l15;
        a[m] = *(const bf16x8_t*)(Ab + rowa * 128 + chunk * 16);
      }
      #pragma unroll
      for (int n = 0; n < 4; n++) {
        int rowb = wc * 64 + n * 16 + l15;
        b[n] = *(const bf16x8_t*)(Bb + rowb * 128 + chunk * 16);
      }
      __builtin_amdgcn_s_setprio(1);
      #pragma unroll
      for (int m = 0; m < 4; m++)
        #pragma unroll
        for (int n = 0; n < 4; n++)
          acc[m][n] = __builtin_amdgcn_mfma_f32_16x16x32_bf16(a[m], b[n], acc[m][n], 0, 0, 0);
      __builtin_amdgcn_s_setprio(0);
    }
    __builtin_amdgcn_sched_barrier(0);
    __builtin_amdgcn_s_barrier();           // all waves done reading buf[cur]
    __builtin_amdgcn_sched_barrier(0);
    if (ks + 2 < 36) stage(ks + 2, cur);    // safe: buf[cur] free; waited 2 iters later
  }
  // epilogue: C/D layout col=lane&15, row=(lane>>4)*4+reg  (C is strip-local)
  #pragma unroll
  for (int m = 0; m < 4; m++)
    #pragma unroll
    for (int j = 0; j < 4; j++) {
      int crow = by * BM2 + wr * 64 + m * 16 + l4 * 4 + j;
      float* cp = C + (size_t)crow * NTOK + bx * BM2 + wc * 64 + l15;
      #pragma unroll
      for (int n = 0; n < 4; n++) cp[n * 16] = acc[m][n][j];
    }
}

// ---- feature top-32: ONE WAVE PER ROW, no __syncthreads --------------------
// 128-bin windowed radix-select (sims in (0,2) => raw bin in [1920,2048)).
// Wave64 is lockstep on CDNA; LDS phases fenced with lgkmcnt(0)+wave_barrier.
__global__ __launch_bounds__(256) void ktopkf(const float* __restrict__ Astrip, int row0,
                                              float* __restrict__ tvo, int* __restrict__ tio) {
  const int wv = threadIdx.x >> 6, lane = threadIdx.x & 63;
  const int r = blockIdx.x * 4 + wv, row = row0 + r;
  __shared__ int   hist[4][NB2];
  __shared__ float cv[4][CANDCAP];
  __shared__ int   ci[4][CANDCAP];
  __shared__ int   ncnt[4];
  const float* arow = Astrip + (size_t)r * NTOK;
  hist[wv][lane] = 0; hist[wv][lane + 64] = 0;
  if (lane == 0) ncnt[wv] = 0;
  wave_fence_lds();
  // pass 1: windowed histogram (bits>>19 order-preserving for v>0)
  for (int q = 0; q < 32; q++) {
    int c = (q * 64 + lane) * 4;
    float4 v4 = *(const float4*)(arow + c);
    float vv[4] = {v4.x, v4.y, v4.z, v4.w};
    #pragma unroll
    for (int e = 0; e < 4; e++) {
      float v = vv[e];
      if (v > 0.0f && (c + e) != row) {
        int b = (int)(__float_as_uint(v) >> 19) - 1920;
        if (b >= 0) atomicAdd(&hist[wv][b], 1);  // v < 2^-7 can't reach top-32
      }
    }
  }
  wave_fence_lds();
  // suffix scan: lane owns bins 2l, 2l+1
  int h0 = hist[wv][2 * lane], h1 = hist[wv][2 * lane + 1];
  int s = h0 + h1;
  #pragma unroll
  for (int o = 1; o < 64; o <<= 1) {
    int t2 = __shfl_down(s, o);
    if (lane + o < 64) s += t2;
  }
  // s = suffix sum of pair-sums from lane l; sNext = from lane l+1
  int sNext = __shfl_down(s, 1);
  if (lane == 63) sNext = 0;
  // suf(2l) = s;  suf(2l+1) = sNext + h1;  suf(2l+2) = sNext
  int tb = -1;
  if ((sNext + h1 >= KF) && (sNext < KF)) tb = 2 * lane + 1;
  else if ((s >= KF) && (sNext + h1 < KF)) tb = 2 * lane;
  #pragma unroll
  for (int o = 32; o > 0; o >>= 1) {
    int ot = __shfl_down(tb, o);
    if (ot > tb) tb = ot;
  }
  tb = __shfl(tb, 0);
  int t = (tb < 0) ? 1 : 1920 + tb;   // fallback: all positives
  // pass 2: collect candidates (re-read; strip is L3-resident)
  for (int q = 0; q < 32; q++) {
    int c = (q * 64 + lane) * 4;
    float4 v4 = *(const float4*)(arow + c);
    float vv[4] = {v4.x, v4.y, v4.z, v4.w};
    #pragma unroll
    for (int e = 0; e < 4; e++) {
      float v = vv[e];
      if (v > 0.0f && (c + e) != row && (int)(__float_as_uint(v) >> 19) >= t) {
        int p = atomicAdd(&ncnt[wv], 1);
        if (p < CANDCAP) { cv[wv][p] = v; ci[wv][p] = c + e; }
      }
    }
  }
  wave_fence_lds();
  int nc = ncnt[wv]; if (nc > CANDCAP) nc = CANDCAP;
  // exact rank among candidates (value desc, index asc); lane handles 2
  #pragma unroll
  for (int h = 0; h < 2; h++) {
    int cidx = h * 64 + lane;
    if (cidx < nc) {
      float v = cv[wv][cidx]; int idx = ci[wv][cidx];
      int rank = 0;
      for (int j = 0; j < nc; j++)
        if (gt_pair(cv[wv][j], ci[wv][j], v, idx)) rank++;
      if (rank < KF) {
        tvo[(size_t)row * KF + rank] = v;
        tio[(size_t)row * KF + rank] = idx;
      }
    }
  }
  int wrote = nc < KF ? nc : KF;
  for (int k = wrote + lane; k < KF; k += 64) {
    tvo[(size_t)row * KF + k] = 0.0f;
    tio[(size_t)row * KF + k] = -1;
  }
}

// ---- CSR build -------------------------------------------------------------
__global__ __launch_bounds__(256) void kcnt(const int* __restrict__ tio,
                                            int* __restrict__ cnt) {
  int t = blockIdx.x * 256 + threadIdx.x;
  int j = tio[t];
  if (j >= 0) {
    int i = t >> 5;
    atomicAdd(&cnt[i], 1);
    atomicAdd(&cnt[j], 1);
  }
}

__global__ __launch_bounds__(1024) void kscan(const int* __restrict__ cnt,
                                              int* __restrict__ offs,
                                              int* __restrict__ cur) {
  __shared__ int part[1024];
  int tid = threadIdx.x;
  int base = tid * 8;
  int loc[8]; int s = 0;
  #pragma unroll
  for (int q = 0; q < 8; q++) { loc[q] = s; s += cnt[base + q]; }
  part[tid] = s;
  __syncthreads();
  for (int o = 1; o < 1024; o <<= 1) {
    int v = 0;
    if (tid >= o) v = part[tid - o];
    __syncthreads();
    if (tid >= o) part[tid] += v;
    __syncthreads();
  }
  int pre = (tid == 0) ? 0 : part[tid - 1];
  #pragma unroll
  for (int q = 0; q < 8; q++) { offs[base + q] = pre + loc[q]; cur[base + q] = pre + loc[q]; }
  if (tid == 1023) offs[NTOK] = part[1023];
}

__global__ __launch_bounds__(256) void kscat(const float* __restrict__ tvo,
                                             const int* __restrict__ tio,
                                             int* __restrict__ cur,
                                             int* __restrict__ colA,
                                             float* __restrict__ valA) {
  int t = blockIdx.x * 256 + threadIdx.x;
  int j = tio[t];
  if (j >= 0) {
    int i = t >> 5;
    float v = tvo[t] * 0.5f;
    int p = atomicAdd(&cur[i], 1); colA[p] = j; valA[p] = v;
    int q = atomicAdd(&cur[j], 1); colA[q] = i; valA[q] = v;
  }
}

__global__ __launch_bounds__(256) void kdeg1(const int* __restrict__ offs,
                                             const float* __restrict__ valA,
                                             float* __restrict__ d1) {
  int i = blockIdx.x * 256 + threadIdx.x;
  float s = 0.f;
  int e0 = offs[i], e1 = offs[i + 1];
  for (int e = e0; e < e1; e++) s += valA[e];
  d1[i] = 1.0f / sqrtf(s);
}

// ---- prescale: valA[e] *= d1[i]*d1[j]  (one wave per row) ------------------
__global__ __launch_bounds__(256) void kprescale(const int* __restrict__ offs,
                                                 const int* __restrict__ colA,
                                                 const float* __restrict__ d1,
                                                 float* __restrict__ valA) {
  int i = blockIdx.x * 4 + (threadIdx.x >> 6);
  int lane = threadIdx.x & 63;
  float di = d1[i];
  int e0 = offs[i], e1 = offs[i + 1];
  for (int e = e0 + lane; e < e1; e += 64) valA[e] *= di * d1[colA[e]];
}

// ---- SpMM: GP1 = G1 @ P1 (prescaled weights, LDS edge cache, 8x MLP) -------
__global__ __launch_bounds__(256) void kspmm1(const int* __restrict__ offs,
                                              const int* __restrict__ colA,
                                              const float* __restrict__ valA,
                                              const float* __restrict__ Psi,
                                              float* __restrict__ GP1) {
  int i = blockIdx.x;
  int c = threadIdx.x;
  __shared__ int   sj[128];
  __shared__ float sw[128];
  float acc = 0.f;
  int e0 = offs[i], e1 = offs[i + 1];
  for (int base = e0; base < e1; base += 128) {
    int nb = e1 - base; if (nb > 128) nb = 128;
    __syncthreads();
    if (c < nb) { sj[c] = colA[base + c]; sw[c] = valA[base + c]; }
    __syncthreads();
    int e = 0;
    for (; e + 8 <= nb; e += 8) {
      float p0 = Psi[(size_t)sj[e + 0] * KPSI + c];
      float p1 = Psi[(size_t)sj[e + 1] * KPSI + c];
      float p2 = Psi[(size_t)sj[e + 2] * KPSI + c];
      float p3 = Psi[(size_t)sj[e + 3] * KPSI + c];
      float p4 = Psi[(size_t)sj[e + 4] * KPSI + c];
      float p5 = Psi[(size_t)sj[e + 5] * KPSI + c];
      float p6 = Psi[(size_t)sj[e + 6] * KPSI + c];
      float p7 = Psi[(size_t)sj[e + 7] * KPSI + c];
      acc += sw[e + 0] * p0; acc += sw[e + 1] * p1;
      acc += sw[e + 2] * p2; acc += sw[e + 3] * p3;
      acc += sw[e + 4] * p4; acc += sw[e + 5] * p5;
      acc += sw[e + 6] * p6; acc += sw[e + 7] * p7;
    }
    for (; e + 4 <= nb; e += 4) {
      float p0 = Psi[(size_t)sj[e + 0] * KPSI + c];
      float p1 = Psi[(size_t)sj[e + 1] * KPSI + c];
      float p2 = Psi[(size_t)sj[e + 2] * KPSI + c];
      float p3 = Psi[(size_t)sj[e + 3] * KPSI + c];
      acc += sw[e + 0] * p0; acc += sw[e + 1] * p1;
      acc += sw[e + 2] * p2; acc += sw[e + 3] * p3;
    }
    for (; e < nb; e++) acc += sw[e] * Psi[(size_t)sj[e] * KPSI + c];
  }
  GP1[(size_t)i * KH + c] = acc;
}

// ---- SpMM: GP2 = G2 @ P2 (LDS edge list from bitmap, 8x MLP, SJCAP clamp) --
__global__ __launch_bounds__(256) void kspmm2(const unsigned int* __restrict__ bits,
                                              const float* __restrict__ d2n,
                                              const float* __restrict__ Psi,
                                              float* __restrict__ GP2) {
  int i = blockIdx.x;
  int base = (i >> 10) << 10;
  int c = threadIdx.x;
  __shared__ int   sj[SJCAP];
  __shared__ float sw[SJCAP];
  __shared__ int scnt;
  if (c < 32) {
    unsigned int w = bits[(size_t)i * 32 + c];
    int n = __popc(w);
    int pre = n;
    #pragma unroll
    for (int o = 1; o < 32; o <<= 1) {
      int v = __shfl_up(pre, o);
      if (c >= o) pre += v;
    }
    pre -= n;                          // exclusive prefix over words
    int k = pre;
    while (w) {
      int b = __ffs(w) - 1; w &= w - 1;
      int j = base + c * 32 + b;
      if (k < SJCAP) { sj[k] = j; sw[k] = d2n[j]; }
      k++;
    }
    if (c == 31) scnt = pre + n;
  }
  __syncthreads();
  int nb = scnt; if (nb > SJCAP) nb = SJCAP;
  float acc = 0.f;
  int e = 0;
  for (; e + 8 <= nb; e += 8) {
    float p0 = Psi[(size_t)sj[e + 0] * KPSI + KH + c];
    float p1 = Psi[(size_t)sj[e + 1] * KPSI + KH + c];
    float p2 = Psi[(size_t)sj[e + 2] * KPSI + KH + c];
    float p3 = Psi[(size_t)sj[e + 3] * KPSI + KH + c];
    float p4 = Psi[(size_t)sj[e + 4] * KPSI + KH + c];
    float p5 = Psi[(size_t)sj[e + 5] * KPSI + KH + c];
    float p6 = Psi[(size_t)sj[e + 6] * KPSI + KH + c];
    float p7 = Psi[(size_t)sj[e + 7] * KPSI + KH + c];
    acc += sw[e + 0] * p0; acc += sw[e + 1] * p1;
    acc += sw[e + 2] * p2; acc += sw[e + 3] * p3;
    acc += sw[e + 4] * p4; acc += sw[e + 5] * p5;
    acc += sw[e + 6] * p6; acc += sw[e + 7] * p7;
  }
  for (; e + 4 <= nb; e += 4) {
    float p0 = Psi[(size_t)sj[e + 0] * KPSI + KH + c];
    float p1 = Psi[(size_t)sj[e + 1] * KPSI + KH + c];
    float p2 = Psi[(size_t)sj[e + 2] * KPSI + KH + c];
    float p3 = Psi[(size_t)sj[e + 3] * KPSI + KH + c];
    acc += sw[e + 0] * p0; acc += sw[e + 1] * p1;
    acc += sw[e + 2] * p2; acc += sw[e + 3] * p3;
  }
  for (; e < nb; e++) acc += sw[e] * Psi[(size_t)sj[e] * KPSI + KH + c];
  GP2[(size_t)i * KH + c] = acc * d2n[i];
}

// ---- R = P^T (GP), upper-triangle tiles only (R symmetric; kfinal uses j>=i)
__global__ __launch_bounds__(256) void kR(const float* __restrict__ Psi,
                                          const float* __restrict__ GP1,
                                          const float* __restrict__ GP2,
                                          float* __restrict__ R) {
  static const int tmap[10] = {0,0,0,0,1,1,1,2,2,3};
  static const int nmap[10] = {0,1,2,3,1,2,3,2,3,3};
  int g = blockIdx.z;
  const float* GP = g ? GP2 : GP1;
  int colOff = g ? KH : 0;
  int tile = blockIdx.x;
  int tm0 = tmap[tile] * 64, tn0 = nmap[tile] * 64;
  int k0 = blockIdx.y * 256;
  __shared__ float As2[16][68];
  __shared__ float Bs2[16][68];
  int tid = threadIdx.x;
  int tx = tid & 15, ty = tid >> 4;
  int lkk = tid >> 4, lq = (tid & 15) * 4;
  float acc[4][4] = {};
  for (int kk0 = 0; kk0 < 256; kk0 += 16) {
    int krow = k0 + kk0 + lkk;
    float4 a = *(const float4*)&Psi[(size_t)krow * KPSI + colOff + tm0 + lq];
    float4 b = *(const float4*)&GP[(size_t)krow * KH + tn0 + lq];
    As2[lkk][lq + 0] = a.x; As2[lkk][lq + 1] = a.y; As2[lkk][lq + 2] = a.z; As2[lkk][lq + 3] = a.w;
    Bs2[lkk][lq + 0] = b.x; Bs2[lkk][lq + 1] = b.y; Bs2[lkk][lq + 2] = b.z; Bs2[lkk][lq + 3] = b.w;
    __syncthreads();
    #pragma unroll
    for (int k = 0; k < 16; k++) {
      const float4 av = *(const float4*)&As2[k][ty * 4];
      const float4 bv = *(const float4*)&Bs2[k][tx * 4];
      float aa[4] = {av.x, av.y, av.z, av.w};
      float bb[4] = {bv.x, bv.y, bv.z, bv.w};
      #pragma unroll
      for (int i2 = 0; i2 < 4; i2++)
        #pragma unroll
        for (int j2 = 0; j2 < 4; j2++)
          acc[i2][j2] += aa[i2] * bb[j2];
    }
    __syncthreads();
  }
  #pragma unroll
  for (int i2 = 0; i2 < 4; i2++)
    #pragma unroll
    for (int j2 = 0; j2 < 4; j2++)
      atomicAdd(&R[(size_t)g * KH * KH + (size_t)(tm0 + ty * 4 + i2) * KH + tn0 + tx * 4 + j2],
                acc[i2][j2]);
}

// ---- final: 2-stage parallel fp64 reduction --------------------------------
__global__ __launch_bounds__(256) void kfinal1(const float* __restrict__ R,
                                               double* __restrict__ part) {
  const double s2 = 10.0 / 8192.0;
  int blk = blockIdx.x, tid = threadIdx.x;
  double tr = 0.0, rg = 0.0;
  #pragma unroll
  for (int q = 0; q < 4; q++) {
    int t = blk * 1024 + q * 256 + tid;  // 0..131071
    int t2 = t & 65535;
    int i = t2 >> 8, j = t2 & 255;
    double v = (double)R[t] * s2;
    if (i == j) tr += v;
    else if (j > i) rg += v * v;
  }
  __shared__ double sa[4], sb[4];
  #pragma unroll
  for (int o = 32; o > 0; o >>= 1) { tr += __shfl_down(tr, o); rg += __shfl_down(rg, o); }
  if ((tid & 63) == 0) { sa[tid >> 6] = tr; sb[tid >> 6] = rg; }
  __syncthreads();
  if (tid == 0) {
    part[blk * 2 + 0] = sa[0] + sa[1] + sa[2] + sa[3];
    part[blk * 2 + 1] = sb[0] + sb[1] + sb[2] + sb[3];
  }
}

__global__ __launch_bounds__(128) void kfinal2(const double* __restrict__ part,
                                               float* __restrict__ out) {
  int tid = threadIdx.x;  // 128 threads = 2 waves
  double tr = part[tid * 2 + 0];
  double rg = part[tid * 2 + 1];
  __shared__ double sa[2], sb[2];
  #pragma unroll
  for (int o = 32; o > 0; o >>= 1) { tr += __shfl_down(tr, o); rg += __shfl_down(rg, o); }
  if ((tid & 63) == 0) { sa[tid >> 6] = tr; sb[tid >> 6] = rg; }
  __syncthreads();
  if (tid == 0) {
    tr = sa[0] + sa[1];
    rg = sb[0] + sb[1];
    out[0] = (float)(-tr / 512.0);
    out[1] = (float)((rg / 512.0) * 0.05);
  }
}

// ---------------------------------------------------------------------------
extern "C" void kernel_launch(void* const* d_in, const int* in_sizes, int n_in,
                              void* d_out, int out_size, void* d_ws, size_t ws_size,
                              hipStream_t stream) {
  const float* hf  = (const float*)d_in[0];
  const float* Psi = (const float*)d_in[1];
  const float* im  = (const float*)d_in[2];
  float* out = (float*)d_out;

  char* base = (char*)d_ws;
  size_t off = 0;
  auto alloc = [&](size_t bytes) -> void* {
    void* p = base + off;
    off += (bytes + 255) & ~(size_t)255;
    return p;
  };

  __hip_bfloat16* Xs = (__hip_bfloat16*)alloc((size_t)NTOK * 2 * DFEAT * 2);
  float* tv    = (float*)alloc((size_t)NTOK * KF * 4);
  int*   ti    = (int*)  alloc((size_t)NTOK * KF * 4);
  int*   cnt   = (int*)  alloc((size_t)NTOK * 4);
  int*   offs  = (int*)  alloc((size_t)(NTOK + 1) * 4);
  int*   cur   = (int*)  alloc((size_t)NTOK * 4);
  int*   colA  = (int*)  alloc((size_t)NTOK * KF * 2 * 4);
  float* valA  = (float*)alloc((size_t)NTOK * KF * 2 * 4);
  float* d1    = (float*)alloc((size_t)NTOK * 4);
  float* GP1   = (float*)alloc((size_t)NTOK * KH * 4);
  float* GP2   = (float*)alloc((size_t)NTOK * KH * 4);
  unsigned int* bits = (unsigned int*)alloc((size_t)NTOK * 32 * 4);
  float* d2n   = (float*)alloc((size_t)NTOK * 4);
  float* pf    = (float*)alloc((size_t)2 * BSZ * HW * 8 * 4);
  float* Rm    = (float*)alloc((size_t)2 * KH * KH * 4);
  double* partd = (double*)alloc((size_t)128 * 2 * 8);
  float* Astrip = (float*)(base + off);

  size_t rem = (ws_size > off) ? (ws_size - off) : 0;
  long srows = (long)(rem / ((size_t)NTOK * 4));
  srows &= ~255L;
  if (srows < 256) srows = 256;
  if (srows > SROWS) srows = SROWS;   // keep C-strip L3-resident

  hipMemsetAsync(cnt, 0, (size_t)NTOK * 4, stream);
  hipMemsetAsync(bits, 0, (size_t)NTOK * 32 * 4, stream);
  hipMemsetAsync(Rm, 0, (size_t)2 * KH * KH * 4, stream);

  ksplit<<<NTOK, 256, 0, stream>>>(hf, Xs);
  kpixfeat<<<(BSZ * HW) / 256, 256, 0, stream>>>(im, pf);
  kpixtopk<<<(BSZ * HW * 2) / 4, 256, 0, stream>>>(pf, bits);
  kdeg2<<<NTOK / 256, 256, 0, stream>>>(bits, d2n);

  for (int row0 = 0; row0 < NTOK; row0 += (int)srows) {
    int rows = NTOK - row0;
    if (rows > srows) rows = (int)srows;
    int nwg = (rows / BM2) * (NTOK / BM2);
    kgemm256<<<nwg, 1024, 0, stream>>>(Xs, Astrip, row0, nwg);
    ktopkf<<<rows / 4, 256, 0, stream>>>(Astrip, row0, tv, ti);
  }

  kcnt<<<(NTOK * KF) / 256, 256, 0, stream>>>(ti, cnt);
  kscan<<<1, 1024, 0, stream>>>(cnt, offs, cur);
  kscat<<<(NTOK * KF) / 256, 256, 0, stream>>>(tv, ti, cur, colA, valA);
  kdeg1<<<NTOK / 256, 256, 0, stream>>>(offs, valA, d1);
  kprescale<<<NTOK / 4, 256, 0, stream>>>(offs, colA, d1, valA);
  kspmm1<<<NTOK, 256, 0, stream>>>(offs, colA, valA, Psi, GP1);
  kspmm2<<<NTOK, 256, 0, stream>>>(bits, d2n, Psi, GP2);
  kR<<<dim3(10, 32, 2), 256, 0, stream>>>(Psi, GP1, GP2, Rm);
  kfinal1<<<128, 256, 0, stream>>>(Rm, partd);
  kfinal2<<<1, 128, 0, stream>>>(partd, out);
}

// Round 17
// 702.412 us; speedup vs baseline: 1.1392x; 1.1392x over previous
//
#include <hip/hip_runtime.h>
#include <hip/hip_bf16.h>
#include <cstdint>
#include <cstddef>

#define NTOK 8192
#define DFEAT 768
#define HW 1024
#define BSZ 8
#define KPSI 512
#define KH 256
#define KF 32
#define KPIX 10
#define NB2 128
#define CANDCAP 128
#define BM2 256
#define BK 64
#define SROWS 2048
#define SJCAP 160

typedef __attribute__((ext_vector_type(8))) short bf16x8_t;
typedef __attribute__((ext_vector_type(4))) float f32x4;

__device__ __forceinline__ bool gt_pair(float va, int ia, float vb, int ib) {
  return (va > vb) || (va == vb && ia < ib);
}
__device__ __forceinline__ bool lt_pair(float va, int ia, float vb, int ib) {
  return (va < vb) || (va == vb && ia < ib);
}

__device__ __forceinline__ void gload_lds16(const void* g, void* l) {
  __builtin_amdgcn_global_load_lds((const __attribute__((address_space(1))) void*)g,
                                   (__attribute__((address_space(3))) void*)l, 16, 0, 0);
}

// ---- normalize + bf16 hi/lo split: Y[row] = [hi(768) | lo(768)] ------------
__global__ __launch_bounds__(256) void ksplit(const float* __restrict__ X,
                                              __hip_bfloat16* __restrict__ Y) {
  int row = blockIdx.x;
  int tid = threadIdx.x;
  const float* x = X + (size_t)row * DFEAT;
  float s = 0.f;
  for (int c = tid; c < DFEAT; c += 256) { float v = x[c]; s += v * v; }
  __shared__ float red[4];
  #pragma unroll
  for (int o = 32; o > 0; o >>= 1) s += __shfl_down(s, o);
  if ((tid & 63) == 0) red[tid >> 6] = s;
  __syncthreads();
  if (tid == 0) red[0] = red[0] + red[1] + red[2] + red[3];
  __syncthreads();
  float nrm = sqrtf(red[0]);
  __hip_bfloat16* y = Y + (size_t)row * (2 * DFEAT);
  for (int c = tid; c < DFEAT; c += 256) {
    float v = x[c] / nrm;
    __hip_bfloat16 hi = __float2bfloat16(v);
    __hip_bfloat16 lo = __float2bfloat16(v - __bfloat162float(hi));
    y[c] = hi;
    y[DFEAT + c] = lo;
  }
}

// ---- pixel features: [cfg][img][pix][6] = r,g,b,dw*x,dw*y,sq ---------------
__global__ __launch_bounds__(256) void kpixfeat(const float* __restrict__ im,
                                                float* __restrict__ pf) {
  int t = blockIdx.x * 256 + threadIdx.x;
  int img = t >> 10, p = t & 1023;
  float r = (im[((size_t)img * 3 + 0) * HW + p] + 1.0f) * 0.5f;
  float g = (im[((size_t)img * 3 + 1) * HW + p] + 1.0f) * 0.5f;
  float b = (im[((size_t)img * 3 + 2) * HW + p] + 1.0f) * 0.5f;
  float x = (float)(p & 31) * (1.0f / 31.0f);
  float y = (float)(p >> 5) * (1.0f / 31.0f);
  #pragma unroll
  for (int cfg = 0; cfg < 2; cfg++) {
    float dw = cfg ? 0.1f : 2.0f;
    float xx = x * dw, yy = y * dw;
    float sq = r * r + g * g + b * b + xx * xx + yy * yy;
    float* o = pf + (((size_t)cfg * BSZ + img) * HW + p) * 6;
    o[0] = r; o[1] = g; o[2] = b; o[3] = xx; o[4] = yy; o[5] = sq;
  }
}

// ---- pixel top-10: one wave per (row,cfg), cached per-lane minima ----------
__global__ __launch_bounds__(256) void kpixtopk(const float* __restrict__ pf,
                                                unsigned int* __restrict__ bits) {
  int wglobal = blockIdx.x * 4 + (threadIdx.x >> 6);
  int lane = threadIdx.x & 63;
  int cfg = wglobal & 1;
  int gr = wglobal >> 1;
  int img = gr >> 10, i = gr & 1023;
  const float* base = pf + ((size_t)cfg * BSZ + img) * HW * 6;
  const float* fi = base + (size_t)i * 6;
  float r = fi[0], g = fi[1], b = fi[2], x = fi[3], y = fi[4], sq = fi[5];
  float d[16];
  #pragma unroll
  for (int q = 0; q < 16; q++) {
    int j = q * 64 + lane;
    const float* fj = base + (size_t)j * 6;
    float dot = r * fj[0] + g * fj[1] + b * fj[2] + x * fj[3] + y * fj[4];
    float d2 = fmaxf(sq + fj[5] - 2.0f * dot, 0.0f);
    d[q] = (j == i) ? 3.402823e38f : d2;
  }
  // per-lane cached min (sets only change in the winner's owner lane)
  float bv = 3.402823e38f; int bj = 1 << 30;
  #pragma unroll
  for (int q = 0; q < 16; q++) {
    int j = q * 64 + lane;
    if (lt_pair(d[q], j, bv, bj)) { bv = d[q]; bj = j; }
  }
  for (int k = 0; k < KPIX; k++) {
    float rv = bv; int rj = bj;
    #pragma unroll
    for (int o = 32; o > 0; o >>= 1) {
      float ov = __shfl_down(rv, o); int oj = __shfl_down(rj, o);
      if (lt_pair(ov, oj, rv, rj)) { rv = ov; rj = oj; }
    }
    rj = __shfl(rj, 0);
    if ((rj & 63) == lane) {
      d[rj >> 6] = 3.402823e38f;
      bv = 3.402823e38f; bj = 1 << 30;     // owner rescans its 16
      #pragma unroll
      for (int q = 0; q < 16; q++) {
        int j = q * 64 + lane;
        if (lt_pair(d[q], j, bv, bj)) { bv = d[q]; bj = j; }
      }
    }
    if (lane == 0) {
      atomicOr(&bits[((size_t)img * HW + i) * 32 + (rj >> 5)], 1u << (rj & 31));
      atomicOr(&bits[((size_t)img * HW + rj) * 32 + (i >> 5)], 1u << (i & 31));
    }
  }
}

__global__ __launch_bounds__(256) void kdeg2(const unsigned int* __restrict__ bits,
                                             float* __restrict__ d2n) {
  int i = blockIdx.x * 256 + threadIdx.x;
  int c = 0;
  #pragma unroll
  for (int w = 0; w < 32; w++) c += __popc(bits[(size_t)i * 32 + w]);
  d2n[i] = 1.0f / sqrtf((float)c);
}

// ---- bf16x3 MFMA GEMM, 256x256 tile, 16 waves (4x4), dbuf + counted vmcnt --
// (R11-proven config: BK=64, 128KB LDS, vmcnt(4) depth-2, 0 bank conflicts.)
__global__ __launch_bounds__(1024) void kgemm256(const __hip_bfloat16* __restrict__ X,
                                                 float* __restrict__ C,
                                                 int row0, int nwg) {
  __shared__ __hip_bfloat16 sA[2][BM2 * BK];   // 2 x 32 KB
  __shared__ __hip_bfloat16 sB[2][BM2 * BK];   // 2 x 32 KB
  int cpx = nwg >> 3;
  int flat = blockIdx.x;
  int swz = (flat & 7) * cpx + (flat >> 3);
  int by = swz >> 5, bx = swz & 31;
  int tid = threadIdx.x;
  int wid = tid >> 6, lane = tid & 63;
  int wr = wid >> 2, wc = wid & 3;          // wave tile: 64x64 at (wr*64, wc*64)
  int l15 = lane & 15, l4 = lane >> 4, l7 = lane & 7;
  int srow = tid >> 3, sc = tid & 7;        // staging: 8 threads/row, 128 rows/pass

  f32x4 acc[4][4];
  #pragma unroll
  for (int m = 0; m < 4; m++)
    #pragma unroll
    for (int n = 0; n < 4; n++) acc[m][n] = (f32x4){0.f, 0.f, 0.f, 0.f};

  const size_t arow0 = (size_t)(row0 + by * BM2);
  const size_t brow0 = (size_t)(bx * BM2);

  auto stage = [&](int ks, int buf) {
    int s = ks / 12;
    int k0 = (ks - s * 12) * 64;
    int aoff = (s == 2) ? DFEAT : 0;
    int boff = (s == 1) ? DFEAT : 0;
    #pragma unroll
    for (int i = 0; i < 2; i++) {
      int row = i * 128 + srow;
      int gcol = (sc ^ (row & 7)) * 8;     // inverse-swizzled source (rule #21)
      gload_lds16(X + (arow0 + row) * (2 * DFEAT) + aoff + k0 + gcol,
                  &sA[buf][(size_t)i * 8192 + (tid & ~63) * 8]);
      gload_lds16(X + (brow0 + row) * (2 * DFEAT) + boff + k0 + gcol,
                  &sB[buf][(size_t)i * 8192 + (tid & ~63) * 8]);
    }
  };  // 4 gload_lds per stage

  // depth-2 pipeline: S(ks), S(ks+1) in flight; wait vmcnt(4) => S(ks) landed
  stage(0, 0);
  stage(1, 1);
  for (int ks = 0; ks < 36; ks++) {
    int cur = ks & 1;
    if (ks < 35) { asm volatile("s_waitcnt vmcnt(4)" ::: "memory"); }
    else         { asm volatile("s_waitcnt vmcnt(0)" ::: "memory"); }
    __builtin_amdgcn_sched_barrier(0);
    __builtin_amdgcn_s_barrier();           // all waves: S(ks) landed
    __builtin_amdgcn_sched_barrier(0);
    const char* Ab = (const char*)&sA[cur][0];
    const char* Bb = (const char*)&sB[cur][0];
    #pragma unroll
    for (int kk = 0; kk < 2; kk++) {
      bf16x8_t a[4], b[4];
      int chunk = (l4 + kk * 4) ^ l7;      // swizzled read
      #pragma unroll
      for (int m = 0; m < 4; m++) {
        int rowa = wr * 64 + m * 16 + l15;
        a[m] = *(const bf16x8_t*)(Ab + rowa * 128 + chunk * 16);
      }
      #pragma unroll
      for (int n = 0; n < 4; n++) {
        int rowb = wc * 64 + n * 16 + l15;
        b[n] = *(const bf16x8_t*)(Bb + rowb * 128 + chunk * 16);
      }
      __builtin_amdgcn_s_setprio(1);
      #pragma unroll
      for (int m = 0; m < 4; m++)
        #pragma unroll
        for (int n = 0; n < 4; n++)
          acc[m][n] = __builtin_amdgcn_mfma_f32_16x16x32_bf16(a[m], b[n], acc[m][n], 0, 0, 0);
      __builtin_amdgcn_s_setprio(0);
    }
    __builtin_amdgcn_sched_barrier(0);
    __builtin_amdgcn_s_barrier();           // all waves done reading buf[cur]
    __builtin_amdgcn_sched_barrier(0);
    if (ks + 2 < 36) stage(ks + 2, cur);    // safe: buf[cur] free; waited 2 iters later
  }
  // epilogue: C/D layout col=lane&15, row=(lane>>4)*4+reg  (C is strip-local)
  #pragma unroll
  for (int m = 0; m < 4; m++)
    #pragma unroll
    for (int j = 0; j < 4; j++) {
      int crow = by * BM2 + wr * 64 + m * 16 + l4 * 4 + j;
      float* cp = C + (size_t)crow * NTOK + bx * BM2 + wc * 64 + l15;
      #pragma unroll
      for (int n = 0; n < 4; n++) cp[n * 16] = acc[m][n][j];
    }
}

// ---- feature top-32: 128-bin windowed radix-select, per-wave histograms ----
// (R15-proven: 256 threads/row, 4 per-wave hist copies, reg row cache.)
__global__ __launch_bounds__(256) void ktopkf(const float* __restrict__ Astrip, int row0,
                                              float* __restrict__ tvo, int* __restrict__ tio) {
  const int r = blockIdx.x, row = row0 + r, tid = threadIdx.x;
  __shared__ int hist4[4][NB2];
  __shared__ int suf[NB2];
  __shared__ float cv[CANDCAP];
  __shared__ int   ci[CANDCAP];
  __shared__ int ncnt;
  __shared__ int tsh;
  const int wave = tid >> 6;
  const float* arow = Astrip + (size_t)r * NTOK;
  for (int b = tid; b < 4 * NB2; b += 256) ((int*)hist4)[b] = 0;
  if (tid == 0) ncnt = 0;
  __syncthreads();
  // pass 1: load row into registers + windowed histogram
  float4 v4s[8];
  #pragma unroll
  for (int q = 0; q < 8; q++) {
    int c = (q * 256 + tid) * 4;
    float4 v4 = *(const float4*)(arow + c);
    v4s[q] = v4;
    float vv[4] = {v4.x, v4.y, v4.z, v4.w};
    #pragma unroll
    for (int e = 0; e < 4; e++) {
      float v = vv[e];
      if (v > 0.0f && (c + e) != row) {
        int b = (int)(__float_as_uint(v) >> 19) - 1920;
        if (b >= 0) atomicAdd(&hist4[wave][b], 1);  // v < 2^-7 can't reach top-32
      }
    }
  }
  __syncthreads();
  if (tid < NB2) suf[tid] = hist4[0][tid] + hist4[1][tid] + hist4[2][tid] + hist4[3][tid];
  __syncthreads();
  for (int o = 1; o < NB2; o <<= 1) {
    int v = (tid < NB2 && tid + o < NB2) ? suf[tid + o] : 0;
    __syncthreads();
    if (tid < NB2) suf[tid] += v;
    __syncthreads();
  }
  if (tid < NB2) {
    int tail = (tid + 1 < NB2) ? suf[tid + 1] : 0;
    if (suf[tid] >= KF && tail < KF) tsh = 1920 + tid;   // exactly one writer
  }
  if (tid == 0 && suf[0] < KF) tsh = 1;                  // fallback: all positives
  __syncthreads();
  int t = tsh;
  // pass 2: collect candidates from the register copy (no global re-read)
  #pragma unroll
  for (int q = 0; q < 8; q++) {
    int c = (q * 256 + tid) * 4;
    float vv[4] = {v4s[q].x, v4s[q].y, v4s[q].z, v4s[q].w};
    #pragma unroll
    for (int e = 0; e < 4; e++) {
      float v = vv[e];
      if (v > 0.0f && (c + e) != row && (int)(__float_as_uint(v) >> 19) >= t) {
        int p = atomicAdd(&ncnt, 1);
        if (p < CANDCAP) { cv[p] = v; ci[p] = c + e; }
      }
    }
  }
  __syncthreads();
  int nc = ncnt < CANDCAP ? ncnt : CANDCAP;
  if (tid < nc) {
    float v = cv[tid]; int idx = ci[tid];
    int rank = 0;
    for (int j = 0; j < nc; j++)
      if (gt_pair(cv[j], ci[j], v, idx)) rank++;
    if (rank < KF) {
      tvo[(size_t)row * KF + rank] = v;
      tio[(size_t)row * KF + rank] = idx;
    }
  }
  int wrote = nc < KF ? nc : KF;
  for (int k = wrote + tid; k < KF; k += 256) {
    tvo[(size_t)row * KF + k] = 0.0f;
    tio[(size_t)row * KF + k] = -1;
  }
}

// ---- CSR build -------------------------------------------------------------
__global__ __launch_bounds__(256) void kcnt(const int* __restrict__ tio,
                                            int* __restrict__ cnt) {
  int t = blockIdx.x * 256 + threadIdx.x;
  int j = tio[t];
  if (j >= 0) {
    int i = t >> 5;
    atomicAdd(&cnt[i], 1);
    atomicAdd(&cnt[j], 1);
  }
}

__global__ __launch_bounds__(1024) void kscan(const int* __restrict__ cnt,
                                              int* __restrict__ offs,
                                              int* __restrict__ cur) {
  __shared__ int part[1024];
  int tid = threadIdx.x;
  int base = tid * 8;
  int loc[8]; int s = 0;
  #pragma unroll
  for (int q = 0; q < 8; q++) { loc[q] = s; s += cnt[base + q]; }
  part[tid] = s;
  __syncthreads();
  for (int o = 1; o < 1024; o <<= 1) {
    int v = 0;
    if (tid >= o) v = part[tid - o];
    __syncthreads();
    if (tid >= o) part[tid] += v;
    __syncthreads();
  }
  int pre = (tid == 0) ? 0 : part[tid - 1];
  #pragma unroll
  for (int q = 0; q < 8; q++) { offs[base + q] = pre + loc[q]; cur[base + q] = pre + loc[q]; }
  if (tid == 1023) offs[NTOK] = part[1023];
}

__global__ __launch_bounds__(256) void kscat(const float* __restrict__ tvo,
                                             const int* __restrict__ tio,
                                             int* __restrict__ cur,
                                             int* __restrict__ colA,
                                             float* __restrict__ valA) {
  int t = blockIdx.x * 256 + threadIdx.x;
  int j = tio[t];
  if (j >= 0) {
    int i = t >> 5;
    float v = tvo[t] * 0.5f;
    int p = atomicAdd(&cur[i], 1); colA[p] = j; valA[p] = v;
    int q = atomicAdd(&cur[j], 1); colA[q] = i; valA[q] = v;
  }
}

__global__ __launch_bounds__(256) void kdeg1(const int* __restrict__ offs,
                                             const float* __restrict__ valA,
                                             float* __restrict__ d1) {
  int i = blockIdx.x * 256 + threadIdx.x;
  float s = 0.f;
  int e0 = offs[i], e1 = offs[i + 1];
  for (int e = e0; e < e1; e++) s += valA[e];
  d1[i] = 1.0f / sqrtf(s);
}

// ---- prescale: valA[e] *= d1[i]*d1[j]  (one wave per row) ------------------
__global__ __launch_bounds__(256) void kprescale(const int* __restrict__ offs,
                                                 const int* __restrict__ colA,
                                                 const float* __restrict__ d1,
                                                 float* __restrict__ valA) {
  int i = blockIdx.x * 4 + (threadIdx.x >> 6);
  int lane = threadIdx.x & 63;
  float di = d1[i];
  int e0 = offs[i], e1 = offs[i + 1];
  for (int e = e0 + lane; e < e1; e += 64) valA[e] *= di * d1[colA[e]];
}

// ---- SpMM: GP1 = G1 @ P1 (prescaled weights, LDS edge cache, 8x MLP) -------
__global__ __launch_bounds__(256) void kspmm1(const int* __restrict__ offs,
                                              const int* __restrict__ colA,
                                              const float* __restrict__ valA,
                                              const float* __restrict__ Psi,
                                              float* __restrict__ GP1) {
  int i = blockIdx.x;
  int c = threadIdx.x;
  __shared__ int   sj[128];
  __shared__ float sw[128];
  float acc = 0.f;
  int e0 = offs[i], e1 = offs[i + 1];
  for (int base = e0; base < e1; base += 128) {
    int nb = e1 - base; if (nb > 128) nb = 128;
    __syncthreads();
    if (c < nb) { sj[c] = colA[base + c]; sw[c] = valA[base + c]; }
    __syncthreads();
    int e = 0;
    for (; e + 8 <= nb; e += 8) {
      float p0 = Psi[(size_t)sj[e + 0] * KPSI + c];
      float p1 = Psi[(size_t)sj[e + 1] * KPSI + c];
      float p2 = Psi[(size_t)sj[e + 2] * KPSI + c];
      float p3 = Psi[(size_t)sj[e + 3] * KPSI + c];
      float p4 = Psi[(size_t)sj[e + 4] * KPSI + c];
      float p5 = Psi[(size_t)sj[e + 5] * KPSI + c];
      float p6 = Psi[(size_t)sj[e + 6] * KPSI + c];
      float p7 = Psi[(size_t)sj[e + 7] * KPSI + c];
      acc += sw[e + 0] * p0; acc += sw[e + 1] * p1;
      acc += sw[e + 2] * p2; acc += sw[e + 3] * p3;
      acc += sw[e + 4] * p4; acc += sw[e + 5] * p5;
      acc += sw[e + 6] * p6; acc += sw[e + 7] * p7;
    }
    for (; e + 4 <= nb; e += 4) {
      float p0 = Psi[(size_t)sj[e + 0] * KPSI + c];
      float p1 = Psi[(size_t)sj[e + 1] * KPSI + c];
      float p2 = Psi[(size_t)sj[e + 2] * KPSI + c];
      float p3 = Psi[(size_t)sj[e + 3] * KPSI + c];
      acc += sw[e + 0] * p0; acc += sw[e + 1] * p1;
      acc += sw[e + 2] * p2; acc += sw[e + 3] * p3;
    }
    for (; e < nb; e++) acc += sw[e] * Psi[(size_t)sj[e] * KPSI + c];
  }
  GP1[(size_t)i * KH + c] = acc;
}

// ---- SpMM: GP2 = G2 @ P2 (LDS edge list from bitmap, 8x MLP, SJCAP clamp) --
__global__ __launch_bounds__(256) void kspmm2(const unsigned int* __restrict__ bits,
                                              const float* __restrict__ d2n,
                                              const float* __restrict__ Psi,
                                              float* __restrict__ GP2) {
  int i = blockIdx.x;
  int base = (i >> 10) << 10;
  int c = threadIdx.x;
  __shared__ int   sj[SJCAP];
  __shared__ float sw[SJCAP];
  __shared__ int scnt;
  if (c < 32) {
    unsigned int w = bits[(size_t)i * 32 + c];
    int n = __popc(w);
    int pre = n;
    #pragma unroll
    for (int o = 1; o < 32; o <<= 1) {
      int v = __shfl_up(pre, o);
      if (c >= o) pre += v;
    }
    pre -= n;                          // exclusive prefix over words
    int k = pre;
    while (w) {
      int b = __ffs(w) - 1; w &= w - 1;
      int j = base + c * 32 + b;
      if (k < SJCAP) { sj[k] = j; sw[k] = d2n[j]; }
      k++;
    }
    if (c == 31) scnt = pre + n;
  }
  __syncthreads();
  int nb = scnt; if (nb > SJCAP) nb = SJCAP;
  float acc = 0.f;
  int e = 0;
  for (; e + 8 <= nb; e += 8) {
    float p0 = Psi[(size_t)sj[e + 0] * KPSI + KH + c];
    float p1 = Psi[(size_t)sj[e + 1] * KPSI + KH + c];
    float p2 = Psi[(size_t)sj[e + 2] * KPSI + KH + c];
    float p3 = Psi[(size_t)sj[e + 3] * KPSI + KH + c];
    float p4 = Psi[(size_t)sj[e + 4] * KPSI + KH + c];
    float p5 = Psi[(size_t)sj[e + 5] * KPSI + KH + c];
    float p6 = Psi[(size_t)sj[e + 6] * KPSI + KH + c];
    float p7 = Psi[(size_t)sj[e + 7] * KPSI + KH + c];
    acc += sw[e + 0] * p0; acc += sw[e + 1] * p1;
    acc += sw[e + 2] * p2; acc += sw[e + 3] * p3;
    acc += sw[e + 4] * p4; acc += sw[e + 5] * p5;
    acc += sw[e + 6] * p6; acc += sw[e + 7] * p7;
  }
  for (; e + 4 <= nb; e += 4) {
    float p0 = Psi[(size_t)sj[e + 0] * KPSI + KH + c];
    float p1 = Psi[(size_t)sj[e + 1] * KPSI + KH + c];
    float p2 = Psi[(size_t)sj[e + 2] * KPSI + KH + c];
    float p3 = Psi[(size_t)sj[e + 3] * KPSI + KH + c];
    acc += sw[e + 0] * p0; acc += sw[e + 1] * p1;
    acc += sw[e + 2] * p2; acc += sw[e + 3] * p3;
  }
  for (; e < nb; e++) acc += sw[e] * Psi[(size_t)sj[e] * KPSI + KH + c];
  GP2[(size_t)i * KH + c] = acc * d2n[i];
}

// ---- R = P^T (GP), upper-triangle tiles only (R symmetric; kfinal uses j>=i)
__global__ __launch_bounds__(256) void kR(const float* __restrict__ Psi,
                                          const float* __restrict__ GP1,
                                          const float* __restrict__ GP2,
                                          float* __restrict__ R) {
  static const int tmap[10] = {0,0,0,0,1,1,1,2,2,3};
  static const int nmap[10] = {0,1,2,3,1,2,3,2,3,3};
  int g = blockIdx.z;
  const float* GP = g ? GP2 : GP1;
  int colOff = g ? KH : 0;
  int tile = blockIdx.x;
  int tm0 = tmap[tile] * 64, tn0 = nmap[tile] * 64;
  int k0 = blockIdx.y * 256;
  __shared__ float As2[16][68];
  __shared__ float Bs2[16][68];
  int tid = threadIdx.x;
  int tx = tid & 15, ty = tid >> 4;
  int lkk = tid >> 4, lq = (tid & 15) * 4;
  float acc[4][4] = {};
  for (int kk0 = 0; kk0 < 256; kk0 += 16) {
    int krow = k0 + kk0 + lkk;
    float4 a = *(const float4*)&Psi[(size_t)krow * KPSI + colOff + tm0 + lq];
    float4 b = *(const float4*)&GP[(size_t)krow * KH + tn0 + lq];
    As2[lkk][lq + 0] = a.x; As2[lkk][lq + 1] = a.y; As2[lkk][lq + 2] = a.z; As2[lkk][lq + 3] = a.w;
    Bs2[lkk][lq + 0] = b.x; Bs2[lkk][lq + 1] = b.y; Bs2[lkk][lq + 2] = b.z; Bs2[lkk][lq + 3] = b.w;
    __syncthreads();
    #pragma unroll
    for (int k = 0; k < 16; k++) {
      const float4 av = *(const float4*)&As2[k][ty * 4];
      const float4 bv = *(const float4*)&Bs2[k][tx * 4];
      float aa[4] = {av.x, av.y, av.z, av.w};
      float bb[4] = {bv.x, bv.y, bv.z, bv.w};
      #pragma unroll
      for (int i2 = 0; i2 < 4; i2++)
        #pragma unroll
        for (int j2 = 0; j2 < 4; j2++)
          acc[i2][j2] += aa[i2] * bb[j2];
    }
    __syncthreads();
  }
  #pragma unroll
  for (int i2 = 0; i2 < 4; i2++)
    #pragma unroll
    for (int j2 = 0; j2 < 4; j2++)
      atomicAdd(&R[(size_t)g * KH * KH + (size_t)(tm0 + ty * 4 + i2) * KH + tn0 + tx * 4 + j2],
                acc[i2][j2]);
}

// ---- final: 2-stage parallel fp64 reduction --------------------------------
__global__ __launch_bounds__(256) void kfinal1(const float* __restrict__ R,
                                               double* __restrict__ part) {
  const double s2 = 10.0 / 8192.0;
  int blk = blockIdx.x, tid = threadIdx.x;
  double tr = 0.0, rg = 0.0;
  #pragma unroll
  for (int q = 0; q < 4; q++) {
    int t = blk * 1024 + q * 256 + tid;  // 0..131071
    int t2 = t & 65535;
    int i = t2 >> 8, j = t2 & 255;
    double v = (double)R[t] * s2;
    if (i == j) tr += v;
    else if (j > i) rg += v * v;
  }
  __shared__ double sa[4], sb[4];
  #pragma unroll
  for (int o = 32; o > 0; o >>= 1) { tr += __shfl_down(tr, o); rg += __shfl_down(rg, o); }
  if ((tid & 63) == 0) { sa[tid >> 6] = tr; sb[tid >> 6] = rg; }
  __syncthreads();
  if (tid == 0) {
    part[blk * 2 + 0] = sa[0] + sa[1] + sa[2] + sa[3];
    part[blk * 2 + 1] = sb[0] + sb[1] + sb[2] + sb[3];
  }
}

__global__ __launch_bounds__(128) void kfinal2(const double* __restrict__ part,
                                               float* __restrict__ out) {
  int tid = threadIdx.x;  // 128 threads = 2 waves
  double tr = part[tid * 2 + 0];
  double rg = part[tid * 2 + 1];
  __shared__ double sa[2], sb[2];
  #pragma unroll
  for (int o = 32; o > 0; o >>= 1) { tr += __shfl_down(tr, o); rg += __shfl_down(rg, o); }
  if ((tid & 63) == 0) { sa[tid >> 6] = tr; sb[tid >> 6] = rg; }
  __syncthreads();
  if (tid == 0) {
    tr = sa[0] + sa[1];
    rg = sb[0] + sb[1];
    out[0] = (float)(-tr / 512.0);
    out[1] = (float)((rg / 512.0) * 0.05);
  }
}

// ---------------------------------------------------------------------------
extern "C" void kernel_launch(void* const* d_in, const int* in_sizes, int n_in,
                              void* d_out, int out_size, void* d_ws, size_t ws_size,
                              hipStream_t stream) {
  const float* hf  = (const float*)d_in[0];
  const float* Psi = (const float*)d_in[1];
  const float* im  = (const float*)d_in[2];
  float* out = (float*)d_out;

  char* base = (char*)d_ws;
  size_t off = 0;
  auto alloc = [&](size_t bytes) -> void* {
    void* p = base + off;
    off += (bytes + 255) & ~(size_t)255;
    return p;
  };

  __hip_bfloat16* Xs = (__hip_bfloat16*)alloc((size_t)NTOK * 2 * DFEAT * 2);
  float* tv    = (float*)alloc((size_t)NTOK * KF * 4);
  int*   ti    = (int*)  alloc((size_t)NTOK * KF * 4);
  int*   cnt   = (int*)  alloc((size_t)NTOK * 4);
  int*   offs  = (int*)  alloc((size_t)(NTOK + 1) * 4);
  int*   cur   = (int*)  alloc((size_t)NTOK * 4);
  int*   colA  = (int*)  alloc((size_t)NTOK * KF * 2 * 4);
  float* valA  = (float*)alloc((size_t)NTOK * KF * 2 * 4);
  float* d1    = (float*)alloc((size_t)NTOK * 4);
  float* GP1   = (float*)alloc((size_t)NTOK * KH * 4);
  float* GP2   = (float*)alloc((size_t)NTOK * KH * 4);
  unsigned int* bits = (unsigned int*)alloc((size_t)NTOK * 32 * 4);
  float* d2n   = (float*)alloc((size_t)NTOK * 4);
  float* pf    = (float*)alloc((size_t)2 * BSZ * HW * 6 * 4);
  float* Rm    = (float*)alloc((size_t)2 * KH * KH * 4);
  double* partd = (double*)alloc((size_t)128 * 2 * 8);
  float* Astrip = (float*)(base + off);

  size_t rem = (ws_size > off) ? (ws_size - off) : 0;
  long srows = (long)(rem / ((size_t)NTOK * 4));
  srows &= ~255L;
  if (srows < 256) srows = 256;
  if (srows > SROWS) srows = SROWS;   // keep C-strip L3-resident

  hipMemsetAsync(cnt, 0, (size_t)NTOK * 4, stream);
  hipMemsetAsync(bits, 0, (size_t)NTOK * 32 * 4, stream);
  hipMemsetAsync(Rm, 0, (size_t)2 * KH * KH * 4, stream);

  ksplit<<<NTOK, 256, 0, stream>>>(hf, Xs);
  kpixfeat<<<(BSZ * HW) / 256, 256, 0, stream>>>(im, pf);
  kpixtopk<<<(BSZ * HW * 2) / 4, 256, 0, stream>>>(pf, bits);
  kdeg2<<<NTOK / 256, 256, 0, stream>>>(bits, d2n);

  for (int row0 = 0; row0 < NTOK; row0 += (int)srows) {
    int rows = NTOK - row0;
    if (rows > srows) rows = (int)srows;
    int nwg = (rows / BM2) * (NTOK / BM2);
    kgemm256<<<nwg, 1024, 0, stream>>>(Xs, Astrip, row0, nwg);
    ktopkf<<<rows, 256, 0, stream>>>(Astrip, row0, tv, ti);
  }

  kcnt<<<(NTOK * KF) / 256, 256, 0, stream>>>(ti, cnt);
  kscan<<<1, 1024, 0, stream>>>(cnt, offs, cur);
  kscat<<<(NTOK * KF) / 256, 256, 0, stream>>>(tv, ti, cur, colA, valA);
  kdeg1<<<NTOK / 256, 256, 0, stream>>>(offs, valA, d1);
  kprescale<<<NTOK / 4, 256, 0, stream>>>(offs, colA, d1, valA);
  kspmm1<<<NTOK, 256, 0, stream>>>(offs, colA, valA, Psi, GP1);
  kspmm2<<<NTOK, 256, 0, stream>>>(bits, d2n, Psi, GP2);
  kR<<<dim3(10, 32, 2), 256, 0, stream>>>(Psi, GP1, GP2, Rm);
  kfinal1<<<128, 256, 0, stream>>>(Rm, partd);
  kfinal2<<<1, 128, 0, stream>>>(partd, out);
}

// Round 18
// 702.056 us; speedup vs baseline: 1.1397x; 1.0005x over previous
//
#include <hip/hip_runtime.h>
#include <hip/hip_bf16.h>
#include <cstdint>
#include <cstddef>

#define NTOK 8192
#define DFEAT 768
#define HW 1024
#define BSZ 8
#define KPSI 512
#define KH 256
#define KF 32
#define KPIX 10
#define NB2 128
#define CANDCAP 128
#define BM2 256
#define BK 64
#define SROWS 2048
#define SJCAP 160

typedef __attribute__((ext_vector_type(8))) short bf16x8_t;
typedef __attribute__((ext_vector_type(4))) float f32x4;

__device__ __forceinline__ bool gt_pair(float va, int ia, float vb, int ib) {
  return (va > vb) || (va == vb && ia < ib);
}
__device__ __forceinline__ bool lt_pair(float va, int ia, float vb, int ib) {
  return (va < vb) || (va == vb && ia < ib);
}

__device__ __forceinline__ void gload_lds16(const void* g, void* l) {
  __builtin_amdgcn_global_load_lds((const __attribute__((address_space(1))) void*)g,
                                   (__attribute__((address_space(3))) void*)l, 16, 0, 0);
}

// ---- normalize + bf16 hi/lo split: Y[row] = [hi(768) | lo(768)] ------------
__global__ __launch_bounds__(256) void ksplit(const float* __restrict__ X,
                                              __hip_bfloat16* __restrict__ Y) {
  int row = blockIdx.x;
  int tid = threadIdx.x;
  const float* x = X + (size_t)row * DFEAT;
  float s = 0.f;
  for (int c = tid; c < DFEAT; c += 256) { float v = x[c]; s += v * v; }
  __shared__ float red[4];
  #pragma unroll
  for (int o = 32; o > 0; o >>= 1) s += __shfl_down(s, o);
  if ((tid & 63) == 0) red[tid >> 6] = s;
  __syncthreads();
  if (tid == 0) red[0] = red[0] + red[1] + red[2] + red[3];
  __syncthreads();
  float nrm = sqrtf(red[0]);
  __hip_bfloat16* y = Y + (size_t)row * (2 * DFEAT);
  for (int c = tid; c < DFEAT; c += 256) {
    float v = x[c] / nrm;
    __hip_bfloat16 hi = __float2bfloat16(v);
    __hip_bfloat16 lo = __float2bfloat16(v - __bfloat162float(hi));
    y[c] = hi;
    y[DFEAT + c] = lo;
  }
}

// ---- pixel features: [cfg][img][pix][6] = r,g,b,dw*x,dw*y,sq ---------------
__global__ __launch_bounds__(256) void kpixfeat(const float* __restrict__ im,
                                                float* __restrict__ pf) {
  int t = blockIdx.x * 256 + threadIdx.x;
  int img = t >> 10, p = t & 1023;
  float r = (im[((size_t)img * 3 + 0) * HW + p] + 1.0f) * 0.5f;
  float g = (im[((size_t)img * 3 + 1) * HW + p] + 1.0f) * 0.5f;
  float b = (im[((size_t)img * 3 + 2) * HW + p] + 1.0f) * 0.5f;
  float x = (float)(p & 31) * (1.0f / 31.0f);
  float y = (float)(p >> 5) * (1.0f / 31.0f);
  #pragma unroll
  for (int cfg = 0; cfg < 2; cfg++) {
    float dw = cfg ? 0.1f : 2.0f;
    float xx = x * dw, yy = y * dw;
    float sq = r * r + g * g + b * b + xx * xx + yy * yy;
    float* o = pf + (((size_t)cfg * BSZ + img) * HW + p) * 6;
    o[0] = r; o[1] = g; o[2] = b; o[3] = xx; o[4] = yy; o[5] = sq;
  }
}

// ---- pixel top-10: one wave per (row,cfg), cached per-lane minima ----------
__global__ __launch_bounds__(256) void kpixtopk(const float* __restrict__ pf,
                                                unsigned int* __restrict__ bits) {
  int wglobal = blockIdx.x * 4 + (threadIdx.x >> 6);
  int lane = threadIdx.x & 63;
  int cfg = wglobal & 1;
  int gr = wglobal >> 1;
  int img = gr >> 10, i = gr & 1023;
  const float* base = pf + ((size_t)cfg * BSZ + img) * HW * 6;
  const float* fi = base + (size_t)i * 6;
  float r = fi[0], g = fi[1], b = fi[2], x = fi[3], y = fi[4], sq = fi[5];
  float d[16];
  #pragma unroll
  for (int q = 0; q < 16; q++) {
    int j = q * 64 + lane;
    const float* fj = base + (size_t)j * 6;
    float dot = r * fj[0] + g * fj[1] + b * fj[2] + x * fj[3] + y * fj[4];
    float d2 = fmaxf(sq + fj[5] - 2.0f * dot, 0.0f);
    d[q] = (j == i) ? 3.402823e38f : d2;
  }
  // per-lane cached min (sets only change in the winner's owner lane)
  float bv = 3.402823e38f; int bj = 1 << 30;
  #pragma unroll
  for (int q = 0; q < 16; q++) {
    int j = q * 64 + lane;
    if (lt_pair(d[q], j, bv, bj)) { bv = d[q]; bj = j; }
  }
  for (int k = 0; k < KPIX; k++) {
    float rv = bv; int rj = bj;
    #pragma unroll
    for (int o = 32; o > 0; o >>= 1) {
      float ov = __shfl_down(rv, o); int oj = __shfl_down(rj, o);
      if (lt_pair(ov, oj, rv, rj)) { rv = ov; rj = oj; }
    }
    rj = __shfl(rj, 0);
    if ((rj & 63) == lane) {
      d[rj >> 6] = 3.402823e38f;
      bv = 3.402823e38f; bj = 1 << 30;     // owner rescans its 16
      #pragma unroll
      for (int q = 0; q < 16; q++) {
        int j = q * 64 + lane;
        if (lt_pair(d[q], j, bv, bj)) { bv = d[q]; bj = j; }
      }
    }
    if (lane == 0) {
      atomicOr(&bits[((size_t)img * HW + i) * 32 + (rj >> 5)], 1u << (rj & 31));
      atomicOr(&bits[((size_t)img * HW + rj) * 32 + (i >> 5)], 1u << (i & 31));
    }
  }
}

__global__ __launch_bounds__(256) void kdeg2(const unsigned int* __restrict__ bits,
                                             float* __restrict__ d2n) {
  int i = blockIdx.x * 256 + threadIdx.x;
  int c = 0;
  #pragma unroll
  for (int w = 0; w < 32; w++) c += __popc(bits[(size_t)i * 32 + w]);
  d2n[i] = 1.0f / sqrtf((float)c);
}

// ---- bf16x3 MFMA GEMM, 256x256 tile, 16 waves, SINGLE-BARRIER T3 loop ------
// Per K-step: STAGE(buf[cur^1], ks+1) issued FIRST, then ds_read+MFMA from
// buf[cur], then vmcnt(0)+lgkmcnt(0) + ONE s_barrier.  Race-free: reads hit
// buf[cur], writes hit buf[cur^1] (disjoint); at the barrier each wave's
// stage landed (vmcnt 0) and its reads consumed (lgkmcnt 0).
__global__ __launch_bounds__(1024) void kgemm256(const __hip_bfloat16* __restrict__ X,
                                                 float* __restrict__ C,
                                                 int row0, int nwg) {
  __shared__ __hip_bfloat16 sA[2][BM2 * BK];   // 2 x 32 KB
  __shared__ __hip_bfloat16 sB[2][BM2 * BK];   // 2 x 32 KB
  int cpx = nwg >> 3;
  int flat = blockIdx.x;
  int swz = (flat & 7) * cpx + (flat >> 3);
  int by = swz >> 5, bx = swz & 31;
  int tid = threadIdx.x;
  int wid = tid >> 6, lane = tid & 63;
  int wr = wid >> 2, wc = wid & 3;          // wave tile: 64x64 at (wr*64, wc*64)
  int l15 = lane & 15, l4 = lane >> 4, l7 = lane & 7;
  int srow = tid >> 3, sc = tid & 7;        // staging: 8 threads/row, 128 rows/pass

  f32x4 acc[4][4];
  #pragma unroll
  for (int m = 0; m < 4; m++)
    #pragma unroll
    for (int n = 0; n < 4; n++) acc[m][n] = (f32x4){0.f, 0.f, 0.f, 0.f};

  const size_t arow0 = (size_t)(row0 + by * BM2);
  const size_t brow0 = (size_t)(bx * BM2);

  auto stage = [&](int ks, int buf) {
    int s = ks / 12;
    int k0 = (ks - s * 12) * 64;
    int aoff = (s == 2) ? DFEAT : 0;
    int boff = (s == 1) ? DFEAT : 0;
    #pragma unroll
    for (int i = 0; i < 2; i++) {
      int row = i * 128 + srow;
      int gcol = (sc ^ (row & 7)) * 8;     // inverse-swizzled source (rule #21)
      gload_lds16(X + (arow0 + row) * (2 * DFEAT) + aoff + k0 + gcol,
                  &sA[buf][(size_t)i * 8192 + (tid & ~63) * 8]);
      gload_lds16(X + (brow0 + row) * (2 * DFEAT) + boff + k0 + gcol,
                  &sB[buf][(size_t)i * 8192 + (tid & ~63) * 8]);
    }
  };  // 4 gload_lds per stage

  stage(0, 0);
  asm volatile("s_waitcnt vmcnt(0)" ::: "memory");
  __builtin_amdgcn_sched_barrier(0);
  __builtin_amdgcn_s_barrier();
  __builtin_amdgcn_sched_barrier(0);
  for (int ks = 0; ks < 36; ks++) {
    int cur = ks & 1;
    if (ks + 1 < 36) stage(ks + 1, cur ^ 1);  // issue next-tile loads first
    const char* Ab = (const char*)&sA[cur][0];
    const char* Bb = (const char*)&sB[cur][0];
    #pragma unroll
    for (int kk = 0; kk < 2; kk++) {
      bf16x8_t a[4], b[4];
      int chunk = (l4 + kk * 4) ^ l7;      // swizzled read
      #pragma unroll
      for (int m = 0; m < 4; m++) {
        int rowa = wr * 64 + m * 16 + l15;
        a[m] = *(const bf16x8_t*)(Ab + rowa * 128 + chunk * 16);
      }
      #pragma unroll
      for (int n = 0; n < 4; n++) {
        int rowb = wc * 64 + n * 16 + l15;
        b[n] = *(const bf16x8_t*)(Bb + rowb * 128 + chunk * 16);
      }
      __builtin_amdgcn_s_setprio(1);
      #pragma unroll
      for (int m = 0; m < 4; m++)
        #pragma unroll
        for (int n = 0; n < 4; n++)
          acc[m][n] = __builtin_amdgcn_mfma_f32_16x16x32_bf16(a[m], b[n], acc[m][n], 0, 0, 0);
      __builtin_amdgcn_s_setprio(0);
    }
    __builtin_amdgcn_sched_barrier(0);
    asm volatile("s_waitcnt vmcnt(0) lgkmcnt(0)" ::: "memory");
    __builtin_amdgcn_sched_barrier(0);
    __builtin_amdgcn_s_barrier();           // single barrier per K-step
    __builtin_amdgcn_sched_barrier(0);
  }
  // epilogue: C/D layout col=lane&15, row=(lane>>4)*4+reg  (C is strip-local)
  #pragma unroll
  for (int m = 0; m < 4; m++)
    #pragma unroll
    for (int j = 0; j < 4; j++) {
      int crow = by * BM2 + wr * 64 + m * 16 + l4 * 4 + j;
      float* cp = C + (size_t)crow * NTOK + bx * BM2 + wc * 64 + l15;
      #pragma unroll
      for (int n = 0; n < 4; n++) cp[n * 16] = acc[m][n][j];
    }
}

// ---- feature top-32: 128-bin windowed radix-select, per-wave histograms ----
// (R15-proven: 256 threads/row, 4 per-wave hist copies, reg row cache.)
__global__ __launch_bounds__(256) void ktopkf(const float* __restrict__ Astrip, int row0,
                                              float* __restrict__ tvo, int* __restrict__ tio) {
  const int r = blockIdx.x, row = row0 + r, tid = threadIdx.x;
  __shared__ int hist4[4][NB2];
  __shared__ int suf[NB2];
  __shared__ float cv[CANDCAP];
  __shared__ int   ci[CANDCAP];
  __shared__ int ncnt;
  __shared__ int tsh;
  const int wave = tid >> 6;
  const float* arow = Astrip + (size_t)r * NTOK;
  for (int b = tid; b < 4 * NB2; b += 256) ((int*)hist4)[b] = 0;
  if (tid == 0) ncnt = 0;
  __syncthreads();
  // pass 1: load row into registers + windowed histogram
  float4 v4s[8];
  #pragma unroll
  for (int q = 0; q < 8; q++) {
    int c = (q * 256 + tid) * 4;
    float4 v4 = *(const float4*)(arow + c);
    v4s[q] = v4;
    float vv[4] = {v4.x, v4.y, v4.z, v4.w};
    #pragma unroll
    for (int e = 0; e < 4; e++) {
      float v = vv[e];
      if (v > 0.0f && (c + e) != row) {
        int b = (int)(__float_as_uint(v) >> 19) - 1920;
        if (b >= 0) atomicAdd(&hist4[wave][b], 1);  // v < 2^-7 can't reach top-32
      }
    }
  }
  __syncthreads();
  if (tid < NB2) suf[tid] = hist4[0][tid] + hist4[1][tid] + hist4[2][tid] + hist4[3][tid];
  __syncthreads();
  for (int o = 1; o < NB2; o <<= 1) {
    int v = (tid < NB2 && tid + o < NB2) ? suf[tid + o] : 0;
    __syncthreads();
    if (tid < NB2) suf[tid] += v;
    __syncthreads();
  }
  if (tid < NB2) {
    int tail = (tid + 1 < NB2) ? suf[tid + 1] : 0;
    if (suf[tid] >= KF && tail < KF) tsh = 1920 + tid;   // exactly one writer
  }
  if (tid == 0 && suf[0] < KF) tsh = 1;                  // fallback: all positives
  __syncthreads();
  int t = tsh;
  // pass 2: collect candidates from the register copy (no global re-read)
  #pragma unroll
  for (int q = 0; q < 8; q++) {
    int c = (q * 256 + tid) * 4;
    float vv[4] = {v4s[q].x, v4s[q].y, v4s[q].z, v4s[q].w};
    #pragma unroll
    for (int e = 0; e < 4; e++) {
      float v = vv[e];
      if (v > 0.0f && (c + e) != row && (int)(__float_as_uint(v) >> 19) >= t) {
        int p = atomicAdd(&ncnt, 1);
        if (p < CANDCAP) { cv[p] = v; ci[p] = c + e; }
      }
    }
  }
  __syncthreads();
  int nc = ncnt < CANDCAP ? ncnt : CANDCAP;
  if (tid < nc) {
    float v = cv[tid]; int idx = ci[tid];
    int rank = 0;
    for (int j = 0; j < nc; j++)
      if (gt_pair(cv[j], ci[j], v, idx)) rank++;
    if (rank < KF) {
      tvo[(size_t)row * KF + rank] = v;
      tio[(size_t)row * KF + rank] = idx;
    }
  }
  int wrote = nc < KF ? nc : KF;
  for (int k = wrote + tid; k < KF; k += 256) {
    tvo[(size_t)row * KF + k] = 0.0f;
    tio[(size_t)row * KF + k] = -1;
  }
}

// ---- CSR build -------------------------------------------------------------
__global__ __launch_bounds__(256) void kcnt(const int* __restrict__ tio,
                                            int* __restrict__ cnt) {
  int t = blockIdx.x * 256 + threadIdx.x;
  int j = tio[t];
  if (j >= 0) {
    int i = t >> 5;
    atomicAdd(&cnt[i], 1);
    atomicAdd(&cnt[j], 1);
  }
}

__global__ __launch_bounds__(1024) void kscan(const int* __restrict__ cnt,
                                              int* __restrict__ offs,
                                              int* __restrict__ cur) {
  __shared__ int part[1024];
  int tid = threadIdx.x;
  int base = tid * 8;
  int loc[8]; int s = 0;
  #pragma unroll
  for (int q = 0; q < 8; q++) { loc[q] = s; s += cnt[base + q]; }
  part[tid] = s;
  __syncthreads();
  for (int o = 1; o < 1024; o <<= 1) {
    int v = 0;
    if (tid >= o) v = part[tid - o];
    __syncthreads();
    if (tid >= o) part[tid] += v;
    __syncthreads();
  }
  int pre = (tid == 0) ? 0 : part[tid - 1];
  #pragma unroll
  for (int q = 0; q < 8; q++) { offs[base + q] = pre + loc[q]; cur[base + q] = pre + loc[q]; }
  if (tid == 1023) offs[NTOK] = part[1023];
}

__global__ __launch_bounds__(256) void kscat(const float* __restrict__ tvo,
                                             const int* __restrict__ tio,
                                             int* __restrict__ cur,
                                             int* __restrict__ colA,
                                             float* __restrict__ valA) {
  int t = blockIdx.x * 256 + threadIdx.x;
  int j = tio[t];
  if (j >= 0) {
    int i = t >> 5;
    float v = tvo[t] * 0.5f;
    int p = atomicAdd(&cur[i], 1); colA[p] = j; valA[p] = v;
    int q = atomicAdd(&cur[j], 1); colA[q] = i; valA[q] = v;
  }
}

__global__ __launch_bounds__(256) void kdeg1(const int* __restrict__ offs,
                                             const float* __restrict__ valA,
                                             float* __restrict__ d1) {
  int i = blockIdx.x * 256 + threadIdx.x;
  float s = 0.f;
  int e0 = offs[i], e1 = offs[i + 1];
  for (int e = e0; e < e1; e++) s += valA[e];
  d1[i] = 1.0f / sqrtf(s);
}

// ---- prescale: valA[e] *= d1[i]*d1[j]  (one wave per row) ------------------
__global__ __launch_bounds__(256) void kprescale(const int* __restrict__ offs,
                                                 const int* __restrict__ colA,
                                                 const float* __restrict__ d1,
                                                 float* __restrict__ valA) {
  int i = blockIdx.x * 4 + (threadIdx.x >> 6);
  int lane = threadIdx.x & 63;
  float di = d1[i];
  int e0 = offs[i], e1 = offs[i + 1];
  for (int e = e0 + lane; e < e1; e += 64) valA[e] *= di * d1[colA[e]];
}

// ---- SpMM: GP1 = G1 @ P1 (prescaled weights, LDS edge cache, 8x MLP) -------
__global__ __launch_bounds__(256) void kspmm1(const int* __restrict__ offs,
                                              const int* __restrict__ colA,
                                              const float* __restrict__ valA,
                                              const float* __restrict__ Psi,
                                              float* __restrict__ GP1) {
  int i = blockIdx.x;
  int c = threadIdx.x;
  __shared__ int   sj[128];
  __shared__ float sw[128];
  float acc = 0.f;
  int e0 = offs[i], e1 = offs[i + 1];
  for (int base = e0; base < e1; base += 128) {
    int nb = e1 - base; if (nb > 128) nb = 128;
    __syncthreads();
    if (c < nb) { sj[c] = colA[base + c]; sw[c] = valA[base + c]; }
    __syncthreads();
    int e = 0;
    for (; e + 8 <= nb; e += 8) {
      float p0 = Psi[(size_t)sj[e + 0] * KPSI + c];
      float p1 = Psi[(size_t)sj[e + 1] * KPSI + c];
      float p2 = Psi[(size_t)sj[e + 2] * KPSI + c];
      float p3 = Psi[(size_t)sj[e + 3] * KPSI + c];
      float p4 = Psi[(size_t)sj[e + 4] * KPSI + c];
      float p5 = Psi[(size_t)sj[e + 5] * KPSI + c];
      float p6 = Psi[(size_t)sj[e + 6] * KPSI + c];
      float p7 = Psi[(size_t)sj[e + 7] * KPSI + c];
      acc += sw[e + 0] * p0; acc += sw[e + 1] * p1;
      acc += sw[e + 2] * p2; acc += sw[e + 3] * p3;
      acc += sw[e + 4] * p4; acc += sw[e + 5] * p5;
      acc += sw[e + 6] * p6; acc += sw[e + 7] * p7;
    }
    for (; e + 4 <= nb; e += 4) {
      float p0 = Psi[(size_t)sj[e + 0] * KPSI + c];
      float p1 = Psi[(size_t)sj[e + 1] * KPSI + c];
      float p2 = Psi[(size_t)sj[e + 2] * KPSI + c];
      float p3 = Psi[(size_t)sj[e + 3] * KPSI + c];
      acc += sw[e + 0] * p0; acc += sw[e + 1] * p1;
      acc += sw[e + 2] * p2; acc += sw[e + 3] * p3;
    }
    for (; e < nb; e++) acc += sw[e] * Psi[(size_t)sj[e] * KPSI + c];
  }
  GP1[(size_t)i * KH + c] = acc;
}

// ---- SpMM: GP2 = G2 @ P2 (LDS edge list from bitmap, 8x MLP, SJCAP clamp) --
__global__ __launch_bounds__(256) void kspmm2(const unsigned int* __restrict__ bits,
                                              const float* __restrict__ d2n,
                                              const float* __restrict__ Psi,
                                              float* __restrict__ GP2) {
  int i = blockIdx.x;
  int base = (i >> 10) << 10;
  int c = threadIdx.x;
  __shared__ int   sj[SJCAP];
  __shared__ float sw[SJCAP];
  __shared__ int scnt;
  if (c < 32) {
    unsigned int w = bits[(size_t)i * 32 + c];
    int n = __popc(w);
    int pre = n;
    #pragma unroll
    for (int o = 1; o < 32; o <<= 1) {
      int v = __shfl_up(pre, o);
      if (c >= o) pre += v;
    }
    pre -= n;                          // exclusive prefix over words
    int k = pre;
    while (w) {
      int b = __ffs(w) - 1; w &= w - 1;
      int j = base + c * 32 + b;
      if (k < SJCAP) { sj[k] = j; sw[k] = d2n[j]; }
      k++;
    }
    if (c == 31) scnt = pre + n;
  }
  __syncthreads();
  int nb = scnt; if (nb > SJCAP) nb = SJCAP;
  float acc = 0.f;
  int e = 0;
  for (; e + 8 <= nb; e += 8) {
    float p0 = Psi[(size_t)sj[e + 0] * KPSI + KH + c];
    float p1 = Psi[(size_t)sj[e + 1] * KPSI + KH + c];
    float p2 = Psi[(size_t)sj[e + 2] * KPSI + KH + c];
    float p3 = Psi[(size_t)sj[e + 3] * KPSI + KH + c];
    float p4 = Psi[(size_t)sj[e + 4] * KPSI + KH + c];
    float p5 = Psi[(size_t)sj[e + 5] * KPSI + KH + c];
    float p6 = Psi[(size_t)sj[e + 6] * KPSI + KH + c];
    float p7 = Psi[(size_t)sj[e + 7] * KPSI + KH + c];
    acc += sw[e + 0] * p0; acc += sw[e + 1] * p1;
    acc += sw[e + 2] * p2; acc += sw[e + 3] * p3;
    acc += sw[e + 4] * p4; acc += sw[e + 5] * p5;
    acc += sw[e + 6] * p6; acc += sw[e + 7] * p7;
  }
  for (; e + 4 <= nb; e += 4) {
    float p0 = Psi[(size_t)sj[e + 0] * KPSI + KH + c];
    float p1 = Psi[(size_t)sj[e + 1] * KPSI + KH + c];
    float p2 = Psi[(size_t)sj[e + 2] * KPSI + KH + c];
    float p3 = Psi[(size_t)sj[e + 3] * KPSI + KH + c];
    acc += sw[e + 0] * p0; acc += sw[e + 1] * p1;
    acc += sw[e + 2] * p2; acc += sw[e + 3] * p3;
  }
  for (; e < nb; e++) acc += sw[e] * Psi[(size_t)sj[e] * KPSI + KH + c];
  GP2[(size_t)i * KH + c] = acc * d2n[i];
}

// ---- R = P^T (GP), upper-triangle tiles only (R symmetric; kfinal uses j>=i)
__global__ __launch_bounds__(256) void kR(const float* __restrict__ Psi,
                                          const float* __restrict__ GP1,
                                          const float* __restrict__ GP2,
                                          float* __restrict__ R) {
  static const int tmap[10] = {0,0,0,0,1,1,1,2,2,3};
  static const int nmap[10] = {0,1,2,3,1,2,3,2,3,3};
  int g = blockIdx.z;
  const float* GP = g ? GP2 : GP1;
  int colOff = g ? KH : 0;
  int tile = blockIdx.x;
  int tm0 = tmap[tile] * 64, tn0 = nmap[tile] * 64;
  int k0 = blockIdx.y * 256;
  __shared__ float As2[16][68];
  __shared__ float Bs2[16][68];
  int tid = threadIdx.x;
  int tx = tid & 15, ty = tid >> 4;
  int lkk = tid >> 4, lq = (tid & 15) * 4;
  float acc[4][4] = {};
  for (int kk0 = 0; kk0 < 256; kk0 += 16) {
    int krow = k0 + kk0 + lkk;
    float4 a = *(const float4*)&Psi[(size_t)krow * KPSI + colOff + tm0 + lq];
    float4 b = *(const float4*)&GP[(size_t)krow * KH + tn0 + lq];
    As2[lkk][lq + 0] = a.x; As2[lkk][lq + 1] = a.y; As2[lkk][lq + 2] = a.z; As2[lkk][lq + 3] = a.w;
    Bs2[lkk][lq + 0] = b.x; Bs2[lkk][lq + 1] = b.y; Bs2[lkk][lq + 2] = b.z; Bs2[lkk][lq + 3] = b.w;
    __syncthreads();
    #pragma unroll
    for (int k = 0; k < 16; k++) {
      const float4 av = *(const float4*)&As2[k][ty * 4];
      const float4 bv = *(const float4*)&Bs2[k][tx * 4];
      float aa[4] = {av.x, av.y, av.z, av.w};
      float bb[4] = {bv.x, bv.y, bv.z, bv.w};
      #pragma unroll
      for (int i2 = 0; i2 < 4; i2++)
        #pragma unroll
        for (int j2 = 0; j2 < 4; j2++)
          acc[i2][j2] += aa[i2] * bb[j2];
    }
    __syncthreads();
  }
  #pragma unroll
  for (int i2 = 0; i2 < 4; i2++)
    #pragma unroll
    for (int j2 = 0; j2 < 4; j2++)
      atomicAdd(&R[(size_t)g * KH * KH + (size_t)(tm0 + ty * 4 + i2) * KH + tn0 + tx * 4 + j2],
                acc[i2][j2]);
}

// ---- final: 2-stage parallel fp64 reduction --------------------------------
__global__ __launch_bounds__(256) void kfinal1(const float* __restrict__ R,
                                               double* __restrict__ part) {
  const double s2 = 10.0 / 8192.0;
  int blk = blockIdx.x, tid = threadIdx.x;
  double tr = 0.0, rg = 0.0;
  #pragma unroll
  for (int q = 0; q < 4; q++) {
    int t = blk * 1024 + q * 256 + tid;  // 0..131071
    int t2 = t & 65535;
    int i = t2 >> 8, j = t2 & 255;
    double v = (double)R[t] * s2;
    if (i == j) tr += v;
    else if (j > i) rg += v * v;
  }
  __shared__ double sa[4], sb[4];
  #pragma unroll
  for (int o = 32; o > 0; o >>= 1) { tr += __shfl_down(tr, o); rg += __shfl_down(rg, o); }
  if ((tid & 63) == 0) { sa[tid >> 6] = tr; sb[tid >> 6] = rg; }
  __syncthreads();
  if (tid == 0) {
    part[blk * 2 + 0] = sa[0] + sa[1] + sa[2] + sa[3];
    part[blk * 2 + 1] = sb[0] + sb[1] + sb[2] + sb[3];
  }
}

__global__ __launch_bounds__(128) void kfinal2(const double* __restrict__ part,
                                               float* __restrict__ out) {
  int tid = threadIdx.x;  // 128 threads = 2 waves
  double tr = part[tid * 2 + 0];
  double rg = part[tid * 2 + 1];
  __shared__ double sa[2], sb[2];
  #pragma unroll
  for (int o = 32; o > 0; o >>= 1) { tr += __shfl_down(tr, o); rg += __shfl_down(rg, o); }
  if ((tid & 63) == 0) { sa[tid >> 6] = tr; sb[tid >> 6] = rg; }
  __syncthreads();
  if (tid == 0) {
    tr = sa[0] + sa[1];
    rg = sb[0] + sb[1];
    out[0] = (float)(-tr / 512.0);
    out[1] = (float)((rg / 512.0) * 0.05);
  }
}

// ---------------------------------------------------------------------------
extern "C" void kernel_launch(void* const* d_in, const int* in_sizes, int n_in,
                              void* d_out, int out_size, void* d_ws, size_t ws_size,
                              hipStream_t stream) {
  const float* hf  = (const float*)d_in[0];
  const float* Psi = (const float*)d_in[1];
  const float* im  = (const float*)d_in[2];
  float* out = (float*)d_out;

  char* base = (char*)d_ws;
  size_t off = 0;
  auto alloc = [&](size_t bytes) -> void* {
    void* p = base + off;
    off += (bytes + 255) & ~(size_t)255;
    return p;
  };

  __hip_bfloat16* Xs = (__hip_bfloat16*)alloc((size_t)NTOK * 2 * DFEAT * 2);
  float* tv    = (float*)alloc((size_t)NTOK * KF * 4);
  int*   ti    = (int*)  alloc((size_t)NTOK * KF * 4);
  int*   cnt   = (int*)  alloc((size_t)NTOK * 4);
  int*   offs  = (int*)  alloc((size_t)(NTOK + 1) * 4);
  int*   cur   = (int*)  alloc((size_t)NTOK * 4);
  int*   colA  = (int*)  alloc((size_t)NTOK * KF * 2 * 4);
  float* valA  = (float*)alloc((size_t)NTOK * KF * 2 * 4);
  float* d1    = (float*)alloc((size_t)NTOK * 4);
  float* GP1   = (float*)alloc((size_t)NTOK * KH * 4);
  float* GP2   = (float*)alloc((size_t)NTOK * KH * 4);
  unsigned int* bits = (unsigned int*)alloc((size_t)NTOK * 32 * 4);
  float* d2n   = (float*)alloc((size_t)NTOK * 4);
  float* pf    = (float*)alloc((size_t)2 * BSZ * HW * 6 * 4);
  float* Rm    = (float*)alloc((size_t)2 * KH * KH * 4);
  double* partd = (double*)alloc((size_t)128 * 2 * 8);
  float* Astrip = (float*)(base + off);

  size_t rem = (ws_size > off) ? (ws_size - off) : 0;
  long srows = (long)(rem / ((size_t)NTOK * 4));
  srows &= ~255L;
  if (srows < 256) srows = 256;
  if (srows > SROWS) srows = SROWS;   // keep C-strip L3-resident

  hipMemsetAsync(cnt, 0, (size_t)NTOK * 4, stream);
  hipMemsetAsync(bits, 0, (size_t)NTOK * 32 * 4, stream);
  hipMemsetAsync(Rm, 0, (size_t)2 * KH * KH * 4, stream);

  ksplit<<<NTOK, 256, 0, stream>>>(hf, Xs);
  kpixfeat<<<(BSZ * HW) / 256, 256, 0, stream>>>(im, pf);
  kpixtopk<<<(BSZ * HW * 2) / 4, 256, 0, stream>>>(pf, bits);
  kdeg2<<<NTOK / 256, 256, 0, stream>>>(bits, d2n);

  for (int row0 = 0; row0 < NTOK; row0 += (int)srows) {
    int rows = NTOK - row0;
    if (rows > srows) rows = (int)srows;
    int nwg = (rows / BM2) * (NTOK / BM2);
    kgemm256<<<nwg, 1024, 0, stream>>>(Xs, Astrip, row0, nwg);
    ktopkf<<<rows, 256, 0, stream>>>(Astrip, row0, tv, ti);
  }

  kcnt<<<(NTOK * KF) / 256, 256, 0, stream>>>(ti, cnt);
  kscan<<<1, 1024, 0, stream>>>(cnt, offs, cur);
  kscat<<<(NTOK * KF) / 256, 256, 0, stream>>>(tv, ti, cur, colA, valA);
  kdeg1<<<NTOK / 256, 256, 0, stream>>>(offs, valA, d1);
  kprescale<<<NTOK / 4, 256, 0, stream>>>(offs, colA, d1, valA);
  kspmm1<<<NTOK, 256, 0, stream>>>(offs, colA, valA, Psi, GP1);
  kspmm2<<<NTOK, 256, 0, stream>>>(bits, d2n, Psi, GP2);
  kR<<<dim3(10, 32, 2), 256, 0, stream>>>(Psi, GP1, GP2, Rm);
  kfinal1<<<128, 256, 0, stream>>>(Rm, partd);
  kfinal2<<<1, 128, 0, stream>>>(partd, out);
}